// Round 5
// baseline (422.905 us; speedup 1.0000x reference)
//
#include <hip/hip_runtime.h>
#include <hip/hip_bf16.h>

typedef __bf16 bf16;
typedef __bf16 bf16x8 __attribute__((ext_vector_type(8)));
typedef __bf16 bf16x4 __attribute__((ext_vector_type(4)));
typedef float  f32x4  __attribute__((ext_vector_type(4)));

struct hl { bf16 h, l; };
__device__ __forceinline__ hl split1(float v) {
    hl r;
    r.h = (bf16)v;
    r.l = (bf16)(v - (float)r.h);
    return r;
}

__device__ __forceinline__ void glds16(const void* g, void* l) {
    __builtin_amdgcn_global_load_lds(
        (const __attribute__((address_space(1))) void*)g,
        (__attribute__((address_space(3))) void*)l, 16, 0, 0);
}

// ---------------------------------------------------------------------------
// C[M,N] = A[M,K] * B[N,K]^T with split-bf16 (3-MFMA) products.
// AMODE/BMODE: 0 = f32 operand, reg-staged split into padded LDS (stride 40)
//              1 = bf16 hi/lo planes, global_load_lds into linear LDS (stride 32)
// OMODE:       0 = f32 C     1 = split C into bf16 hi/lo planes
// 1D grid with bijective XCD swizzle (gridDim.x % 8 == 0 in all launches).
// ---------------------------------------------------------------------------
template<int AMODE, int BMODE, int OMODE>
__global__ __launch_bounds__(256) void gemm3(
    const float* __restrict__ Af, const bf16* __restrict__ Agh, const bf16* __restrict__ Agl,
    const float* __restrict__ Bf, const bf16* __restrict__ Bgh, const bf16* __restrict__ Bgl,
    float* __restrict__ Cf, bf16* __restrict__ Cgh, bf16* __restrict__ Cgl,
    int M, int N, int K, long sAz, long sBz, long sCz, int nbm, int nbn)
{
    constexpr int LDA = AMODE ? 32 : 40;
    constexpr int LDB = BMODE ? 32 : 40;
    __shared__ __align__(16) bf16 Ah[128 * LDA];
    __shared__ __align__(16) bf16 Al[128 * LDA];
    __shared__ __align__(16) bf16 Bh[128 * LDB];
    __shared__ __align__(16) bf16 Bl[128 * LDB];

    const int tid  = threadIdx.x;
    const int lane = tid & 63;
    const int wid  = tid >> 6;
    const int wm   = wid >> 1;          // 2x2 waves, each owns 64x64 output
    const int wn   = wid & 1;

    // XCD-aware swizzle: each XCD gets a contiguous run of work items.
    const int qq = gridDim.x >> 3;
    const int sw = (blockIdx.x & 7) * qq + (blockIdx.x >> 3);
    const int z  = sw / (nbm * nbn);
    const int tt = sw % (nbm * nbn);
    const int m0 = (tt / nbn) * 128;
    const int n0 = (tt % nbn) * 128;

    // ---- staging pointer setup ----
    const float* aF[4]; const float* bF[4];
    const bf16 *aH0, *aH1, *aL0, *aL1, *bH0, *bH1, *bL0, *bL1;
    if constexpr (AMODE == 0) {
#pragma unroll
        for (int j = 0; j < 4; ++j) {
            const int idx = j * 256 + tid;
            aF[j] = Af + (long)z * sAz + (long)(m0 + (idx >> 3)) * K + (idx & 7) * 4;
        }
    } else {
        const int r0 = tid >> 2, c0 = (tid & 3) * 8;
        aH0 = Agh + (long)z * sAz + (long)(m0 + r0) * K + c0;
        aH1 = aH0 + (long)64 * K;
        aL0 = Agl + (long)z * sAz + (long)(m0 + r0) * K + c0;
        aL1 = aL0 + (long)64 * K;
    }
    if constexpr (BMODE == 0) {
#pragma unroll
        for (int j = 0; j < 4; ++j) {
            const int idx = j * 256 + tid;
            bF[j] = Bf + (long)z * sBz + (long)(n0 + (idx >> 3)) * K + (idx & 7) * 4;
        }
    } else {
        const int r0 = tid >> 2, c0 = (tid & 3) * 8;
        bH0 = Bgh + (long)z * sBz + (long)(n0 + r0) * K + c0;
        bH1 = bH0 + (long)64 * K;
        bL0 = Bgl + (long)z * sBz + (long)(n0 + r0) * K + c0;
        bL1 = bL0 + (long)64 * K;
    }

    f32x4 acc[4][4];
#pragma unroll
    for (int i = 0; i < 4; ++i)
#pragma unroll
        for (int j = 0; j < 4; ++j) acc[i][j] = (f32x4)0.0f;

    const int lr = lane & 15;
    const int lk = (lane >> 4) * 8;

    for (int kt = 0; kt < K; kt += 32) {
        __syncthreads();
        // ---- stage A ----
        if constexpr (AMODE == 1) {
            glds16(aH0, &Ah[tid * 8]); glds16(aH1, &Ah[(256 + tid) * 8]);
            glds16(aL0, &Al[tid * 8]); glds16(aL1, &Al[(256 + tid) * 8]);
            aH0 += 32; aH1 += 32; aL0 += 32; aL1 += 32;
        } else {
#pragma unroll
            for (int j = 0; j < 4; ++j) {
                const int idx = j * 256 + tid;
                const int r = idx >> 3, c = (idx & 7) * 4;
                const float4 v = *(const float4*)aF[j]; aF[j] += 32;
                bf16x4 h, l;
                hl s0 = split1(v.x); h.x = s0.h; l.x = s0.l;
                hl s1 = split1(v.y); h.y = s1.h; l.y = s1.l;
                hl s2 = split1(v.z); h.z = s2.h; l.z = s2.l;
                hl s3 = split1(v.w); h.w = s3.h; l.w = s3.l;
                *(bf16x4*)&Ah[r * LDA + c] = h;
                *(bf16x4*)&Al[r * LDA + c] = l;
            }
        }
        // ---- stage B ----
        if constexpr (BMODE == 1) {
            glds16(bH0, &Bh[tid * 8]); glds16(bH1, &Bh[(256 + tid) * 8]);
            glds16(bL0, &Bl[tid * 8]); glds16(bL1, &Bl[(256 + tid) * 8]);
            bH0 += 32; bH1 += 32; bL0 += 32; bL1 += 32;
        } else {
#pragma unroll
            for (int j = 0; j < 4; ++j) {
                const int idx = j * 256 + tid;
                const int r = idx >> 3, c = (idx & 7) * 4;
                const float4 v = *(const float4*)bF[j]; bF[j] += 32;
                bf16x4 h, l;
                hl s0 = split1(v.x); h.x = s0.h; l.x = s0.l;
                hl s1 = split1(v.y); h.y = s1.h; l.y = s1.l;
                hl s2 = split1(v.z); h.z = s2.h; l.z = s2.l;
                hl s3 = split1(v.w); h.w = s3.h; l.w = s3.l;
                *(bf16x4*)&Bh[r * LDB + c] = h;
                *(bf16x4*)&Bl[r * LDB + c] = l;
            }
        }
        __syncthreads();   // compiler emits vmcnt(0)+lgkmcnt(0) drain here

        bf16x8 afh[4], afl[4], bfh[4], bfl[4];
#pragma unroll
        for (int i = 0; i < 4; ++i) {
            afh[i] = *(const bf16x8*)&Ah[(wm * 64 + i * 16 + lr) * LDA + lk];
            afl[i] = *(const bf16x8*)&Al[(wm * 64 + i * 16 + lr) * LDA + lk];
            bfh[i] = *(const bf16x8*)&Bh[(wn * 64 + i * 16 + lr) * LDB + lk];
            bfl[i] = *(const bf16x8*)&Bl[(wn * 64 + i * 16 + lr) * LDB + lk];
        }
#pragma unroll
        for (int i = 0; i < 4; ++i)
#pragma unroll
            for (int j = 0; j < 4; ++j) {
                acc[i][j] = __builtin_amdgcn_mfma_f32_16x16x32_bf16(afh[i], bfh[j], acc[i][j], 0, 0, 0);
                acc[i][j] = __builtin_amdgcn_mfma_f32_16x16x32_bf16(afl[i], bfh[j], acc[i][j], 0, 0, 0);
                acc[i][j] = __builtin_amdgcn_mfma_f32_16x16x32_bf16(afh[i], bfl[j], acc[i][j], 0, 0, 0);
            }
    }

    // ---- epilogue: D mapping col = lane&15, row = (lane>>4)*4 + q ----
    const int rr = (lane >> 4) * 4;
#pragma unroll
    for (int i = 0; i < 4; ++i)
#pragma unroll
        for (int j = 0; j < 4; ++j)
#pragma unroll
            for (int q = 0; q < 4; ++q) {
                const long off = (long)z * sCz
                               + (long)(m0 + wm * 64 + i * 16 + rr + q) * N
                               + (n0 + wn * 64 + j * 16 + (lane & 15));
                if constexpr (OMODE == 0) {
                    Cf[off] = acc[i][j][q];
                } else {
                    hl s = split1(acc[i][j][q]);
                    Cgh[off] = s.h; Cgl[off] = s.l;
                }
            }
}

// ---------------------------------------------------------------------------
// elementwise: f32 -> (hi, lo) bf16 planes
// ---------------------------------------------------------------------------
__global__ __launch_bounds__(256) void split_pair(
    const float* __restrict__ x, bf16* __restrict__ h, bf16* __restrict__ l, long n4)
{
    long i = (long)blockIdx.x * 256 + threadIdx.x;
    const long stride = (long)gridDim.x * 256;
    for (; i < n4; i += stride) {
        const float4 v = ((const float4*)x)[i];
        bf16x4 hh, ll;
        hl s0 = split1(v.x); hh.x = s0.h; ll.x = s0.l;
        hl s1 = split1(v.y); hh.y = s1.h; ll.y = s1.l;
        hl s2 = split1(v.z); hh.z = s2.h; ll.z = s2.l;
        hl s3 = split1(v.w); hh.w = s3.h; ll.w = s3.l;
        ((bf16x4*)h)[i] = hh;
        ((bf16x4*)l)[i] = ll;
    }
}

// ---------------------------------------------------------------------------
// masked softmax, one wave per 1024-elem row (no LDS, shuffle-only reduce)
// rows = 16384, batch = row >> 10
// ---------------------------------------------------------------------------
__global__ __launch_bounds__(256) void softmax_wave(
    float* __restrict__ data, const int* __restrict__ lens)
{
    const int tid  = threadIdx.x;
    const int lane = tid & 63;
    const int row  = blockIdx.x * 4 + (tid >> 6);
    const int len  = lens[row >> 10];
    float* p = data + (long)row * 1024;

    float4 v[4];
#pragma unroll
    for (int q = 0; q < 4; ++q) v[q] = *(const float4*)(p + 4 * (lane + 64 * q));

    float m = -INFINITY;
#pragma unroll
    for (int q = 0; q < 4; ++q) {
        const int base = 4 * (lane + 64 * q);
        if (base + 0 < len) m = fmaxf(m, v[q].x);
        if (base + 1 < len) m = fmaxf(m, v[q].y);
        if (base + 2 < len) m = fmaxf(m, v[q].z);
        if (base + 3 < len) m = fmaxf(m, v[q].w);
    }
#pragma unroll
    for (int off = 32; off >= 1; off >>= 1) m = fmaxf(m, __shfl_xor(m, off));

    float s = 0.0f;
    float4 e[4];
#pragma unroll
    for (int q = 0; q < 4; ++q) {
        const int base = 4 * (lane + 64 * q);
        e[q].x = (base + 0 < len) ? __expf(v[q].x - m) : 0.0f;
        e[q].y = (base + 1 < len) ? __expf(v[q].y - m) : 0.0f;
        e[q].z = (base + 2 < len) ? __expf(v[q].z - m) : 0.0f;
        e[q].w = (base + 3 < len) ? __expf(v[q].w - m) : 0.0f;
        s += e[q].x + e[q].y + e[q].z + e[q].w;
    }
#pragma unroll
    for (int off = 32; off >= 1; off >>= 1) s += __shfl_xor(s, off);

    const float inv = 1.0f / s;
#pragma unroll
    for (int q = 0; q < 4; ++q) {
        float4 o; o.x = e[q].x * inv; o.y = e[q].y * inv; o.z = e[q].z * inv; o.w = e[q].w * inv;
        *(float4*)(p + 4 * (lane + 64 * q)) = o;
    }
}

// ---------------------------------------------------------------------------
// round-2 proven fallback GEMM (tier C)
// ---------------------------------------------------------------------------
__global__ __launch_bounds__(256) void gemm_bt_split(
    const float* __restrict__ A, const float* __restrict__ Bmat,
    float* __restrict__ C, int M, int N, int K,
    long sAz, long sBz, long sCz)
{
    __shared__ __align__(16) bf16 Ah[128][40];
    __shared__ __align__(16) bf16 Al[128][40];
    __shared__ __align__(16) bf16 Bh[128][40];
    __shared__ __align__(16) bf16 Bl[128][40];

    const int tid  = threadIdx.x;
    const int lane = tid & 63;
    const int wid  = tid >> 6;
    const int wm   = wid >> 1;
    const int wn   = wid & 1;
    const int z    = blockIdx.z;
    const long aBase = (long)z * sAz;
    const long bBase = (long)z * sBz;
    const long cBase = (long)z * sCz;
    const int m0 = blockIdx.x * 128;
    const int n0 = blockIdx.y * 128;

    f32x4 acc[4][4];
#pragma unroll
    for (int i = 0; i < 4; ++i)
#pragma unroll
        for (int j = 0; j < 4; ++j) acc[i][j] = (f32x4)0.0f;

    const int lr = lane & 15;
    const int lk = (lane >> 4) * 8;

    for (int kt = 0; kt < K; kt += 32) {
        __syncthreads();
#pragma unroll
        for (int j = 0; j < 4; ++j) {
            const int idx = j * 256 + tid;
            const int r   = idx >> 3;
            const int c   = (idx & 7) * 4;
            const float4 va = *(const float4*)(A    + aBase + (long)(m0 + r) * K + kt + c);
            const float4 vb = *(const float4*)(Bmat + bBase + (long)(n0 + r) * K + kt + c);
            bf16x4 ah, al, bh, bl;
            hl a0 = split1(va.x); ah.x = a0.h; al.x = a0.l;
            hl a1 = split1(va.y); ah.y = a1.h; al.y = a1.l;
            hl a2 = split1(va.z); ah.z = a2.h; al.z = a2.l;
            hl a3 = split1(va.w); ah.w = a3.h; al.w = a3.l;
            hl b0 = split1(vb.x); bh.x = b0.h; bl.x = b0.l;
            hl b1 = split1(vb.y); bh.y = b1.h; bl.y = b1.l;
            hl b2 = split1(vb.z); bh.z = b2.h; bl.z = b2.l;
            hl b3 = split1(vb.w); bh.w = b3.h; bl.w = b3.l;
            *(bf16x4*)&Ah[r][c] = ah; *(bf16x4*)&Al[r][c] = al;
            *(bf16x4*)&Bh[r][c] = bh; *(bf16x4*)&Bl[r][c] = bl;
        }
        __syncthreads();

        bf16x8 afh[4], afl[4], bfh[4], bfl[4];
#pragma unroll
        for (int i = 0; i < 4; ++i) {
            afh[i] = *(const bf16x8*)&Ah[wm * 64 + i * 16 + lr][lk];
            afl[i] = *(const bf16x8*)&Al[wm * 64 + i * 16 + lr][lk];
            bfh[i] = *(const bf16x8*)&Bh[wn * 64 + i * 16 + lr][lk];
            bfl[i] = *(const bf16x8*)&Bl[wn * 64 + i * 16 + lr][lk];
        }
#pragma unroll
        for (int i = 0; i < 4; ++i)
#pragma unroll
            for (int j = 0; j < 4; ++j) {
                acc[i][j] = __builtin_amdgcn_mfma_f32_16x16x32_bf16(afh[i], bfh[j], acc[i][j], 0, 0, 0);
                acc[i][j] = __builtin_amdgcn_mfma_f32_16x16x32_bf16(afl[i], bfh[j], acc[i][j], 0, 0, 0);
                acc[i][j] = __builtin_amdgcn_mfma_f32_16x16x32_bf16(afh[i], bfl[j], acc[i][j], 0, 0, 0);
            }
    }

    const int rr = (lane >> 4) * 4;
#pragma unroll
    for (int i = 0; i < 4; ++i)
#pragma unroll
        for (int j = 0; j < 4; ++j)
#pragma unroll
            for (int q = 0; q < 4; ++q)
                C[cBase + (long)(m0 + wm * 64 + i * 16 + rr + q) * N
                        + (n0 + wn * 64 + j * 16 + (lane & 15))] = acc[i][j][q];
}

extern "C" void kernel_launch(void* const* d_in, const int* in_sizes, int n_in,
                              void* d_out, int out_size, void* d_ws, size_t ws_size,
                              hipStream_t stream)
{
    const float* source         = (const float*)d_in[0];  // [16,1024,1024]
    const float* memory_bank    = (const float*)d_in[1];  // [16,1024,1024]
    const int*   memory_lengths = (const int*)  d_in[2];  // [16]
    const float* W_in           = (const float*)d_in[3];  // [1024,1024]
    float* out = (float*)d_out;                           // [16,1024,1024]
    char*  ws  = (char*)d_ws;

    const size_t MB = 1ull << 20;
    const long Z = 1024 * 1024;   // per-batch plane stride (elements)

    if (ws_size >= 197 * MB) {
        // tier A+: everything pre-split, all GEMM staging via global_load_lds
        bf16* htH = (bf16*)(ws);            bf16* htL = (bf16*)(ws + 32 * MB);
        bf16* WH  = (bf16*)(ws + 64 * MB);  bf16* WL  = (bf16*)(ws + 66 * MB);
        bf16* mbH = (bf16*)(ws + 68 * MB);  bf16* mbL = (bf16*)(ws + 100 * MB);
        bf16* srH = (bf16*)(ws + 132 * MB); bf16* srL = (bf16*)(ws + 164 * MB);
        split_pair<<<512,  256, 0, stream>>>(W_in,        WH,  WL,  (1l  << 20) / 4);
        split_pair<<<2048, 256, 0, stream>>>(memory_bank, mbH, mbL, (16l << 20) / 4);
        split_pair<<<2048, 256, 0, stream>>>(source,      srH, srL, (16l << 20) / 4);
        gemm3<1,1,1><<<1024, 256, 0, stream>>>(nullptr, srH, srL, nullptr, WH, WL,
            nullptr, htH, htL, 16384, 1024, 1024, 0, 0, 0, 128, 8);
        gemm3<1,1,0><<<1024, 256, 0, stream>>>(nullptr, htH, htL, nullptr, mbH, mbL,
            out, nullptr, nullptr, 1024, 1024, 1024, Z, Z, Z, 8, 8);
    } else if (ws_size >= 133 * MB) {
        // tier A: W + memory_bank pre-split; GEMM1 A reg-split from f32
        bf16* htH = (bf16*)(ws);            bf16* htL = (bf16*)(ws + 32 * MB);
        bf16* WH  = (bf16*)(ws + 64 * MB);  bf16* WL  = (bf16*)(ws + 66 * MB);
        bf16* mbH = (bf16*)(ws + 68 * MB);  bf16* mbL = (bf16*)(ws + 100 * MB);
        split_pair<<<512,  256, 0, stream>>>(W_in,        WH,  WL,  (1l  << 20) / 4);
        split_pair<<<2048, 256, 0, stream>>>(memory_bank, mbH, mbL, (16l << 20) / 4);
        gemm3<0,1,1><<<1024, 256, 0, stream>>>(source, nullptr, nullptr, nullptr, WH, WL,
            nullptr, htH, htL, 16384, 1024, 1024, 0, 0, 0, 128, 8);
        gemm3<1,1,0><<<1024, 256, 0, stream>>>(nullptr, htH, htL, nullptr, mbH, mbL,
            out, nullptr, nullptr, 1024, 1024, 1024, Z, Z, Z, 8, 8);
    } else if (ws_size >= 69 * MB) {
        // tier B: only W pre-split + ht planes; GEMM2 B reg-split from f32
        bf16* htH = (bf16*)(ws);            bf16* htL = (bf16*)(ws + 32 * MB);
        bf16* WH  = (bf16*)(ws + 64 * MB);  bf16* WL  = (bf16*)(ws + 66 * MB);
        split_pair<<<512, 256, 0, stream>>>(W_in, WH, WL, (1l << 20) / 4);
        gemm3<0,1,1><<<1024, 256, 0, stream>>>(source, nullptr, nullptr, nullptr, WH, WL,
            nullptr, htH, htL, 16384, 1024, 1024, 0, 0, 0, 128, 8);
        gemm3<1,0,0><<<1024, 256, 0, stream>>>(nullptr, htH, htL, memory_bank, nullptr, nullptr,
            out, nullptr, nullptr, 1024, 1024, 1024, Z, Z, Z, 8, 8);
    } else {
        // tier C: round-2 proven fallback
        float* ht = (float*)ws;
        gemm_bt_split<<<dim3(128, 8, 1), 256, 0, stream>>>(
            source, W_in, ht, 16384, 1024, 1024, 0, 0, 0);
        gemm_bt_split<<<dim3(8, 8, 16), 256, 0, stream>>>(
            ht, memory_bank, out, 1024, 1024, 1024, Z, Z, Z);
    }

    softmax_wave<<<4096, 256, 0, stream>>>(out, memory_lengths);
}

// Round 7
// 415.475 us; speedup vs baseline: 1.0179x; 1.0179x over previous
//
#include <hip/hip_runtime.h>
#include <hip/hip_bf16.h>

typedef __bf16 bf16;
typedef __bf16 bf16x8 __attribute__((ext_vector_type(8)));
typedef __bf16 bf16x4 __attribute__((ext_vector_type(4)));
typedef float  f32x4  __attribute__((ext_vector_type(4)));

struct hl { bf16 h, l; };
__device__ __forceinline__ hl split1(float v) {
    hl r;
    r.h = (bf16)v;
    r.l = (bf16)(v - (float)r.h);
    return r;
}

__device__ __forceinline__ void glds16(const void* g, void* l) {
    __builtin_amdgcn_global_load_lds(
        (const __attribute__((address_space(1))) void*)g,
        (__attribute__((address_space(3))) void*)l, 16, 0, 0);
}

// ---------------------------------------------------------------------------
// C[M,N] = A[M,K] * B[N,K]^T with split-bf16 (3-MFMA) products.
// AMODE/BMODE: 0 = f32 operand, reg-staged split into padded LDS (stride 40)
//              1 = bf16 hi/lo planes, global_load_lds into linear LDS (stride 32)
//                  with XOR bank-swizzle: linear LDS dest + inverse-swizzled
//                  global SOURCE col + swizzled READ col (rule: both sides).
//                  swizzle: byte ^= ((row & 6) << 3)  [16B-block select bits]
// OMODE:       0 = f32 C     1 = split C into bf16 hi/lo planes
// 1D grid with bijective XCD swizzle (gridDim.x % 8 == 0 in all launches).
// ---------------------------------------------------------------------------
template<int AMODE, int BMODE, int OMODE>
__global__ __launch_bounds__(256) void gemm3(
    const float* __restrict__ Af, const bf16* __restrict__ Agh, const bf16* __restrict__ Agl,
    const float* __restrict__ Bf, const bf16* __restrict__ Bgh, const bf16* __restrict__ Bgl,
    float* __restrict__ Cf, bf16* __restrict__ Cgh, bf16* __restrict__ Cgl,
    int M, int N, int K, long sAz, long sBz, long sCz, int nbm, int nbn)
{
    constexpr int LDA = AMODE ? 32 : 40;
    constexpr int LDB = BMODE ? 32 : 40;
    __shared__ __align__(16) bf16 Ah[128 * LDA];
    __shared__ __align__(16) bf16 Al[128 * LDA];
    __shared__ __align__(16) bf16 Bh[128 * LDB];
    __shared__ __align__(16) bf16 Bl[128 * LDB];

    const int tid  = threadIdx.x;
    const int lane = tid & 63;
    const int wid  = tid >> 6;
    const int wm   = wid >> 1;          // 2x2 waves, each owns 64x64 output
    const int wn   = wid & 1;

    // XCD-aware swizzle: each XCD gets a contiguous run of work items.
    const int qq = gridDim.x >> 3;
    const int sw = (blockIdx.x & 7) * qq + (blockIdx.x >> 3);
    const int z  = sw / (nbm * nbn);
    const int tt = sw % (nbm * nbn);
    const int m0 = (tt / nbn) * 128;
    const int n0 = (tt % nbn) * 128;

    // staging geometry for mode-1: thread t -> LDS row r0 = t>>2, 16B-chunk t&3.
    // inverse-swizzled SOURCE col (bf16 elems): ((t&3)*16 ^ ((r0&6)<<3)) / 2
    const int r0  = tid >> 2;
    const int c0s = ((((tid & 3) * 16) ^ ((r0 & 6) << 3)) >> 1);

    // ---- staging pointer setup ----
    const float* aF[4]; const float* bF[4];
    const bf16 *aH0, *aH1, *aL0, *aL1, *bH0, *bH1, *bL0, *bL1;
    if constexpr (AMODE == 0) {
#pragma unroll
        for (int j = 0; j < 4; ++j) {
            const int idx = j * 256 + tid;
            aF[j] = Af + (long)z * sAz + (long)(m0 + (idx >> 3)) * K + (idx & 7) * 4;
        }
    } else {
        aH0 = Agh + (long)z * sAz + (long)(m0 + r0) * K + c0s;
        aH1 = aH0 + (long)64 * K;
        aL0 = Agl + (long)z * sAz + (long)(m0 + r0) * K + c0s;
        aL1 = aL0 + (long)64 * K;
    }
    if constexpr (BMODE == 0) {
#pragma unroll
        for (int j = 0; j < 4; ++j) {
            const int idx = j * 256 + tid;
            bF[j] = Bf + (long)z * sBz + (long)(n0 + (idx >> 3)) * K + (idx & 7) * 4;
        }
    } else {
        bH0 = Bgh + (long)z * sBz + (long)(n0 + r0) * K + c0s;
        bH1 = bH0 + (long)64 * K;
        bL0 = Bgl + (long)z * sBz + (long)(n0 + r0) * K + c0s;
        bL1 = bL0 + (long)64 * K;
    }

    f32x4 acc[4][4];
#pragma unroll
    for (int i = 0; i < 4; ++i)
#pragma unroll
        for (int j = 0; j < 4; ++j) acc[i][j] = (f32x4)0.0f;

    const int lr = lane & 15;
    const int lk = (lane >> 4) * 8;
    // swizzled READ col (loop-invariant per thread, elems)
    const int lkA = AMODE ? (lk ^ ((lr & 6) << 2)) : lk;
    const int lkB = BMODE ? (lk ^ ((lr & 6) << 2)) : lk;

    for (int kt = 0; kt < K; kt += 32) {
        __syncthreads();
        // ---- stage A ----
        if constexpr (AMODE == 1) {
            glds16(aH0, &Ah[tid * 8]); glds16(aH1, &Ah[(256 + tid) * 8]);
            glds16(aL0, &Al[tid * 8]); glds16(aL1, &Al[(256 + tid) * 8]);
            aH0 += 32; aH1 += 32; aL0 += 32; aL1 += 32;
        } else {
#pragma unroll
            for (int j = 0; j < 4; ++j) {
                const int idx = j * 256 + tid;
                const int r = idx >> 3, c = (idx & 7) * 4;
                const float4 v = *(const float4*)aF[j]; aF[j] += 32;
                bf16x4 h, l;
                hl s0 = split1(v.x); h.x = s0.h; l.x = s0.l;
                hl s1 = split1(v.y); h.y = s1.h; l.y = s1.l;
                hl s2 = split1(v.z); h.z = s2.h; l.z = s2.l;
                hl s3 = split1(v.w); h.w = s3.h; l.w = s3.l;
                *(bf16x4*)&Ah[r * LDA + c] = h;
                *(bf16x4*)&Al[r * LDA + c] = l;
            }
        }
        // ---- stage B ----
        if constexpr (BMODE == 1) {
            glds16(bH0, &Bh[tid * 8]); glds16(bH1, &Bh[(256 + tid) * 8]);
            glds16(bL0, &Bl[tid * 8]); glds16(bL1, &Bl[(256 + tid) * 8]);
            bH0 += 32; bH1 += 32; bL0 += 32; bL1 += 32;
        } else {
#pragma unroll
            for (int j = 0; j < 4; ++j) {
                const int idx = j * 256 + tid;
                const int r = idx >> 3, c = (idx & 7) * 4;
                const float4 v = *(const float4*)bF[j]; bF[j] += 32;
                bf16x4 h, l;
                hl s0 = split1(v.x); h.x = s0.h; l.x = s0.l;
                hl s1 = split1(v.y); h.y = s1.h; l.y = s1.l;
                hl s2 = split1(v.z); h.z = s2.h; l.z = s2.l;
                hl s3 = split1(v.w); h.w = s3.h; l.w = s3.l;
                *(bf16x4*)&Bh[r * LDB + c] = h;
                *(bf16x4*)&Bl[r * LDB + c] = l;
            }
        }
        __syncthreads();   // compiler emits vmcnt(0)+lgkmcnt(0) drain here

        bf16x8 afh[4], afl[4], bfh[4], bfl[4];
#pragma unroll
        for (int i = 0; i < 4; ++i) {
            afh[i] = *(const bf16x8*)&Ah[(wm * 64 + i * 16 + lr) * LDA + lkA];
            afl[i] = *(const bf16x8*)&Al[(wm * 64 + i * 16 + lr) * LDA + lkA];
            bfh[i] = *(const bf16x8*)&Bh[(wn * 64 + i * 16 + lr) * LDB + lkB];
            bfl[i] = *(const bf16x8*)&Bl[(wn * 64 + i * 16 + lr) * LDB + lkB];
        }
#pragma unroll
        for (int i = 0; i < 4; ++i)
#pragma unroll
            for (int j = 0; j < 4; ++j) {
                acc[i][j] = __builtin_amdgcn_mfma_f32_16x16x32_bf16(afh[i], bfh[j], acc[i][j], 0, 0, 0);
                acc[i][j] = __builtin_amdgcn_mfma_f32_16x16x32_bf16(afl[i], bfh[j], acc[i][j], 0, 0, 0);
                acc[i][j] = __builtin_amdgcn_mfma_f32_16x16x32_bf16(afh[i], bfl[j], acc[i][j], 0, 0, 0);
            }
    }

    // ---- epilogue: D mapping col = lane&15, row = (lane>>4)*4 + q ----
    const int rr = (lane >> 4) * 4;
#pragma unroll
    for (int i = 0; i < 4; ++i)
#pragma unroll
        for (int j = 0; j < 4; ++j)
#pragma unroll
            for (int q = 0; q < 4; ++q) {
                const long off = (long)z * sCz
                               + (long)(m0 + wm * 64 + i * 16 + rr + q) * N
                               + (n0 + wn * 64 + j * 16 + (lane & 15));
                if constexpr (OMODE == 0) {
                    Cf[off] = acc[i][j][q];
                } else {
                    hl s = split1(acc[i][j][q]);
                    Cgh[off] = s.h; Cgl[off] = s.l;
                }
            }
}

// ---------------------------------------------------------------------------
// elementwise: f32 -> (hi, lo) bf16 planes
// ---------------------------------------------------------------------------
__global__ __launch_bounds__(256) void split_pair(
    const float* __restrict__ x, bf16* __restrict__ h, bf16* __restrict__ l, long n4)
{
    long i = (long)blockIdx.x * 256 + threadIdx.x;
    const long stride = (long)gridDim.x * 256;
    for (; i < n4; i += stride) {
        const float4 v = ((const float4*)x)[i];
        bf16x4 hh, ll;
        hl s0 = split1(v.x); hh.x = s0.h; ll.x = s0.l;
        hl s1 = split1(v.y); hh.y = s1.h; ll.y = s1.l;
        hl s2 = split1(v.z); hh.z = s2.h; ll.z = s2.l;
        hl s3 = split1(v.w); hh.w = s3.h; ll.w = s3.l;
        ((bf16x4*)h)[i] = hh;
        ((bf16x4*)l)[i] = ll;
    }
}

// ---------------------------------------------------------------------------
// masked softmax, one wave per 1024-elem row (no LDS, shuffle-only reduce)
// rows = 16384, batch = row >> 10
// ---------------------------------------------------------------------------
__global__ __launch_bounds__(256) void softmax_wave(
    float* __restrict__ data, const int* __restrict__ lens)
{
    const int tid  = threadIdx.x;
    const int lane = tid & 63;
    const int row  = blockIdx.x * 4 + (tid >> 6);
    const int len  = lens[row >> 10];
    float* p = data + (long)row * 1024;

    float4 v[4];
#pragma unroll
    for (int q = 0; q < 4; ++q) v[q] = *(const float4*)(p + 4 * (lane + 64 * q));

    float m = -INFINITY;
#pragma unroll
    for (int q = 0; q < 4; ++q) {
        const int base = 4 * (lane + 64 * q);
        if (base + 0 < len) m = fmaxf(m, v[q].x);
        if (base + 1 < len) m = fmaxf(m, v[q].y);
        if (base + 2 < len) m = fmaxf(m, v[q].z);
        if (base + 3 < len) m = fmaxf(m, v[q].w);
    }
#pragma unroll
    for (int off = 32; off >= 1; off >>= 1) m = fmaxf(m, __shfl_xor(m, off));

    float s = 0.0f;
    float4 e[4];
#pragma unroll
    for (int q = 0; q < 4; ++q) {
        const int base = 4 * (lane + 64 * q);
        e[q].x = (base + 0 < len) ? __expf(v[q].x - m) : 0.0f;
        e[q].y = (base + 1 < len) ? __expf(v[q].y - m) : 0.0f;
        e[q].z = (base + 2 < len) ? __expf(v[q].z - m) : 0.0f;
        e[q].w = (base + 3 < len) ? __expf(v[q].w - m) : 0.0f;
        s += e[q].x + e[q].y + e[q].z + e[q].w;
    }
#pragma unroll
    for (int off = 32; off >= 1; off >>= 1) s += __shfl_xor(s, off);

    const float inv = 1.0f / s;
#pragma unroll
    for (int q = 0; q < 4; ++q) {
        float4 o; o.x = e[q].x * inv; o.y = e[q].y * inv; o.z = e[q].z * inv; o.w = e[q].w * inv;
        *(float4*)(p + 4 * (lane + 64 * q)) = o;
    }
}

// ---------------------------------------------------------------------------
// round-2 proven fallback GEMM (tier C)
// ---------------------------------------------------------------------------
__global__ __launch_bounds__(256) void gemm_bt_split(
    const float* __restrict__ A, const float* __restrict__ Bmat,
    float* __restrict__ C, int M, int N, int K,
    long sAz, long sBz, long sCz)
{
    __shared__ __align__(16) bf16 Ah[128][40];
    __shared__ __align__(16) bf16 Al[128][40];
    __shared__ __align__(16) bf16 Bh[128][40];
    __shared__ __align__(16) bf16 Bl[128][40];

    const int tid  = threadIdx.x;
    const int lane = tid & 63;
    const int wid  = tid >> 6;
    const int wm   = wid >> 1;
    const int wn   = wid & 1;
    const int z    = blockIdx.z;
    const long aBase = (long)z * sAz;
    const long bBase = (long)z * sBz;
    const long cBase = (long)z * sCz;
    const int m0 = blockIdx.x * 128;
    const int n0 = blockIdx.y * 128;

    f32x4 acc[4][4];
#pragma unroll
    for (int i = 0; i < 4; ++i)
#pragma unroll
        for (int j = 0; j < 4; ++j) acc[i][j] = (f32x4)0.0f;

    const int lr = lane & 15;
    const int lk = (lane >> 4) * 8;

    for (int kt = 0; kt < K; kt += 32) {
        __syncthreads();
#pragma unroll
        for (int j = 0; j < 4; ++j) {
            const int idx = j * 256 + tid;
            const int r   = idx >> 3;
            const int c   = (idx & 7) * 4;
            const float4 va = *(const float4*)(A    + aBase + (long)(m0 + r) * K + kt + c);
            const float4 vb = *(const float4*)(Bmat + bBase + (long)(n0 + r) * K + kt + c);
            bf16x4 ah, al, bh, bl;
            hl a0 = split1(va.x); ah.x = a0.h; al.x = a0.l;
            hl a1 = split1(va.y); ah.y = a1.h; al.y = a1.l;
            hl a2 = split1(va.z); ah.z = a2.h; al.z = a2.l;
            hl a3 = split1(va.w); ah.w = a3.h; al.w = a3.l;
            hl b0 = split1(vb.x); bh.x = b0.h; bl.x = b0.l;
            hl b1 = split1(vb.y); bh.y = b1.h; bl.y = b1.l;
            hl b2 = split1(vb.z); bh.z = b2.h; bl.z = b2.l;
            hl b3 = split1(vb.w); bh.w = b3.h; bl.w = b3.l;
            *(bf16x4*)&Ah[r][c] = ah; *(bf16x4*)&Al[r][c] = al;
            *(bf16x4*)&Bh[r][c] = bh; *(bf16x4*)&Bl[r][c] = bl;
        }
        __syncthreads();

        bf16x8 afh[4], afl[4], bfh[4], bfl[4];
#pragma unroll
        for (int i = 0; i < 4; ++i) {
            afh[i] = *(const bf16x8*)&Ah[wm * 64 + i * 16 + lr][lk];
            afl[i] = *(const bf16x8*)&Al[wm * 64 + i * 16 + lr][lk];
            bfh[i] = *(const bf16x8*)&Bh[wn * 64 + i * 16 + lr][lk];
            bfl[i] = *(const bf16x8*)&Bl[wn * 64 + i * 16 + lr][lk];
        }
#pragma unroll
        for (int i = 0; i < 4; ++i)
#pragma unroll
            for (int j = 0; j < 4; ++j) {
                acc[i][j] = __builtin_amdgcn_mfma_f32_16x16x32_bf16(afh[i], bfh[j], acc[i][j], 0, 0, 0);
                acc[i][j] = __builtin_amdgcn_mfma_f32_16x16x32_bf16(afl[i], bfh[j], acc[i][j], 0, 0, 0);
                acc[i][j] = __builtin_amdgcn_mfma_f32_16x16x32_bf16(afh[i], bfl[j], acc[i][j], 0, 0, 0);
            }
    }

    const int rr = (lane >> 4) * 4;
#pragma unroll
    for (int i = 0; i < 4; ++i)
#pragma unroll
        for (int j = 0; j < 4; ++j)
#pragma unroll
            for (int q = 0; q < 4; ++q)
                C[cBase + (long)(m0 + wm * 64 + i * 16 + rr + q) * N
                        + (n0 + wn * 64 + j * 16 + (lane & 15))] = acc[i][j][q];
}

extern "C" void kernel_launch(void* const* d_in, const int* in_sizes, int n_in,
                              void* d_out, int out_size, void* d_ws, size_t ws_size,
                              hipStream_t stream)
{
    const float* source         = (const float*)d_in[0];  // [16,1024,1024]
    const float* memory_bank    = (const float*)d_in[1];  // [16,1024,1024]
    const int*   memory_lengths = (const int*)  d_in[2];  // [16]
    const float* W_in           = (const float*)d_in[3];  // [1024,1024]
    float* out = (float*)d_out;                           // [16,1024,1024]
    char*  ws  = (char*)d_ws;

    const size_t MB = 1ull << 20;
    const long Z = 1024 * 1024;   // per-batch plane stride (elements)

    if (ws_size >= 197 * MB) {
        // tier A+: everything pre-split, all GEMM staging via global_load_lds
        bf16* htH = (bf16*)(ws);            bf16* htL = (bf16*)(ws + 32 * MB);
        bf16* WH  = (bf16*)(ws + 64 * MB);  bf16* WL  = (bf16*)(ws + 66 * MB);
        bf16* mbH = (bf16*)(ws + 68 * MB);  bf16* mbL = (bf16*)(ws + 100 * MB);
        bf16* srH = (bf16*)(ws + 132 * MB); bf16* srL = (bf16*)(ws + 164 * MB);
        split_pair<<<512,  256, 0, stream>>>(W_in,        WH,  WL,  (1l  << 20) / 4);
        split_pair<<<2048, 256, 0, stream>>>(memory_bank, mbH, mbL, (16l << 20) / 4);
        split_pair<<<2048, 256, 0, stream>>>(source,      srH, srL, (16l << 20) / 4);
        gemm3<1,1,1><<<1024, 256, 0, stream>>>(nullptr, srH, srL, nullptr, WH, WL,
            nullptr, htH, htL, 16384, 1024, 1024, 0, 0, 0, 128, 8);
        gemm3<1,1,0><<<1024, 256, 0, stream>>>(nullptr, htH, htL, nullptr, mbH, mbL,
            out, nullptr, nullptr, 1024, 1024, 1024, Z, Z, Z, 8, 8);
    } else if (ws_size >= 133 * MB) {
        // tier A: W + memory_bank pre-split; GEMM1 A reg-split from f32
        bf16* htH = (bf16*)(ws);            bf16* htL = (bf16*)(ws + 32 * MB);
        bf16* WH  = (bf16*)(ws + 64 * MB);  bf16* WL  = (bf16*)(ws + 66 * MB);
        bf16* mbH = (bf16*)(ws + 68 * MB);  bf16* mbL = (bf16*)(ws + 100 * MB);
        split_pair<<<512,  256, 0, stream>>>(W_in,        WH,  WL,  (1l  << 20) / 4);
        split_pair<<<2048, 256, 0, stream>>>(memory_bank, mbH, mbL, (16l << 20) / 4);
        gemm3<0,1,1><<<1024, 256, 0, stream>>>(source, nullptr, nullptr, nullptr, WH, WL,
            nullptr, htH, htL, 16384, 1024, 1024, 0, 0, 0, 128, 8);
        gemm3<1,1,0><<<1024, 256, 0, stream>>>(nullptr, htH, htL, nullptr, mbH, mbL,
            out, nullptr, nullptr, 1024, 1024, 1024, Z, Z, Z, 8, 8);
    } else if (ws_size >= 69 * MB) {
        // tier B: only W pre-split + ht planes; GEMM2 B reg-split from f32
        bf16* htH = (bf16*)(ws);            bf16* htL = (bf16*)(ws + 32 * MB);
        bf16* WH  = (bf16*)(ws + 64 * MB);  bf16* WL  = (bf16*)(ws + 66 * MB);
        split_pair<<<512, 256, 0, stream>>>(W_in, WH, WL, (1l << 20) / 4);
        gemm3<0,1,1><<<1024, 256, 0, stream>>>(source, nullptr, nullptr, nullptr, WH, WL,
            nullptr, htH, htL, 16384, 1024, 1024, 0, 0, 0, 128, 8);
        gemm3<1,0,0><<<1024, 256, 0, stream>>>(nullptr, htH, htL, memory_bank, nullptr, nullptr,
            out, nullptr, nullptr, 1024, 1024, 1024, Z, Z, Z, 8, 8);
    } else {
        // tier C: round-2 proven fallback
        float* ht = (float*)ws;
        gemm_bt_split<<<dim3(128, 8, 1), 256, 0, stream>>>(
            source, W_in, ht, 16384, 1024, 1024, 0, 0, 0);
        gemm_bt_split<<<dim3(8, 8, 16), 256, 0, stream>>>(
            ht, memory_bank, out, 1024, 1024, 1024, Z, Z, Z);
    }

    softmax_wave<<<4096, 256, 0, stream>>>(out, memory_lengths);
}

// Round 9
// 413.521 us; speedup vs baseline: 1.0227x; 1.0047x over previous
//
#include <hip/hip_runtime.h>
#include <hip/hip_bf16.h>

typedef __bf16 bf16;
typedef __bf16 bf16x8 __attribute__((ext_vector_type(8)));
typedef __bf16 bf16x4 __attribute__((ext_vector_type(4)));
typedef float  f32x4  __attribute__((ext_vector_type(4)));
typedef float  f32x16 __attribute__((ext_vector_type(16)));

struct hl { bf16 h, l; };
__device__ __forceinline__ hl split1(float v) {
    hl r;
    r.h = (bf16)v;
    r.l = (bf16)(v - (float)r.h);
    return r;
}

__device__ __forceinline__ void glds16(const void* g, void* l) {
    __builtin_amdgcn_global_load_lds(
        (const __attribute__((address_space(1))) void*)g,
        (__attribute__((address_space(3))) void*)l, 16, 0, 0);
}

// ---------------------------------------------------------------------------
// C[M,N] = A[M,K] * B[N,K]^T with split-bf16 (3-MFMA) products, 32x32x16 MFMA.
// AMODE/BMODE: 0 = f32 operand, reg-staged split into padded LDS (stride 40)
//              1 = bf16 hi/lo planes, global_load_lds into linear LDS (stride 32)
//                  with XOR bank-swizzle (inverse-swizzled global src + swizzled read)
// OMODE:       0 = f32 C     1 = split C into bf16 hi/lo planes
// __launch_bounds__(256,4): cap 128 regs/wave -> 4 blocks/CU (kill tail generation)
// ---------------------------------------------------------------------------
template<int AMODE, int BMODE, int OMODE>
__global__ __launch_bounds__(256, 4) void gemm3(
    const float* __restrict__ Af, const bf16* __restrict__ Agh, const bf16* __restrict__ Agl,
    const float* __restrict__ Bf, const bf16* __restrict__ Bgh, const bf16* __restrict__ Bgl,
    float* __restrict__ Cf, bf16* __restrict__ Cgh, bf16* __restrict__ Cgl,
    int M, int N, int K, long sAz, long sBz, long sCz, int nbm, int nbn)
{
    constexpr int LDA = AMODE ? 32 : 40;
    constexpr int LDB = BMODE ? 32 : 40;
    __shared__ __align__(16) bf16 Ah[128 * LDA];
    __shared__ __align__(16) bf16 Al[128 * LDA];
    __shared__ __align__(16) bf16 Bh[128 * LDB];
    __shared__ __align__(16) bf16 Bl[128 * LDB];

    const int tid  = threadIdx.x;
    const int lane = tid & 63;
    const int wid  = tid >> 6;
    const int wm   = wid >> 1;          // 2x2 waves, each owns 64x64 output
    const int wn   = wid & 1;

    // XCD-aware bijective swizzle (gridDim.x % 8 == 0)
    const int qq = gridDim.x >> 3;
    const int sw = (blockIdx.x & 7) * qq + (blockIdx.x >> 3);
    const int z  = sw / (nbm * nbn);
    const int tt = sw % (nbm * nbn);
    const int m0 = (tt / nbn) * 128;
    const int n0 = (tt % nbn) * 128;

    // staging geometry for mode-1: thread t -> LDS row r0 = t>>2, 16B-chunk t&3.
    // inverse-swizzled SOURCE col (bf16 elems): ((t&3)*16 ^ ((r0&6)<<3)) / 2
    const int r0  = tid >> 2;
    const int c0s = ((((tid & 3) * 16) ^ ((r0 & 6) << 3)) >> 1);

    const float* aF[4]; const float* bF[4];
    const bf16 *aH0, *aH1, *aL0, *aL1, *bH0, *bH1, *bL0, *bL1;
    if constexpr (AMODE == 0) {
#pragma unroll
        for (int j = 0; j < 4; ++j) {
            const int idx = j * 256 + tid;
            aF[j] = Af + (long)z * sAz + (long)(m0 + (idx >> 3)) * K + (idx & 7) * 4;
        }
    } else {
        aH0 = Agh + (long)z * sAz + (long)(m0 + r0) * K + c0s;
        aH1 = aH0 + (long)64 * K;
        aL0 = Agl + (long)z * sAz + (long)(m0 + r0) * K + c0s;
        aL1 = aL0 + (long)64 * K;
    }
    if constexpr (BMODE == 0) {
#pragma unroll
        for (int j = 0; j < 4; ++j) {
            const int idx = j * 256 + tid;
            bF[j] = Bf + (long)z * sBz + (long)(n0 + (idx >> 3)) * K + (idx & 7) * 4;
        }
    } else {
        bH0 = Bgh + (long)z * sBz + (long)(n0 + r0) * K + c0s;
        bH1 = bH0 + (long)64 * K;
        bL0 = Bgl + (long)z * sBz + (long)(n0 + r0) * K + c0s;
        bL1 = bL0 + (long)64 * K;
    }

    // ---- 32x32x16 fragment geometry ----
    // A/B frag: row = lane&31 (M for A, N for B), k = (lane>>5)*8 + i
    const int lr32 = lane & 31;
    const int kb8  = (lane >> 5) * 8;
    const int swA  = AMODE ? ((lr32 & 6) << 2) : 0;   // elem-offset XOR (16B granules)
    const int swB  = BMODE ? ((lr32 & 6) << 2) : 0;
    const int aRow0 = (wm * 64 + lr32) * LDA;
    const int aRow1 = aRow0 + 32 * LDA;
    const int bRow0 = (wn * 64 + lr32) * LDB;
    const int bRow1 = bRow0 + 32 * LDB;

    f32x16 acc[2][2];
#pragma unroll
    for (int i = 0; i < 2; ++i)
#pragma unroll
        for (int j = 0; j < 2; ++j) acc[i][j] = (f32x16)0.0f;

    for (int kt = 0; kt < K; kt += 32) {
        __syncthreads();
        // ---- stage A ----
        if constexpr (AMODE == 1) {
            glds16(aH0, &Ah[tid * 8]); glds16(aH1, &Ah[(256 + tid) * 8]);
            glds16(aL0, &Al[tid * 8]); glds16(aL1, &Al[(256 + tid) * 8]);
            aH0 += 32; aH1 += 32; aL0 += 32; aL1 += 32;
        } else {
#pragma unroll
            for (int j = 0; j < 4; ++j) {
                const int idx = j * 256 + tid;
                const int r = idx >> 3, c = (idx & 7) * 4;
                const float4 v = *(const float4*)aF[j]; aF[j] += 32;
                bf16x4 h, l;
                hl s0 = split1(v.x); h.x = s0.h; l.x = s0.l;
                hl s1 = split1(v.y); h.y = s1.h; l.y = s1.l;
                hl s2 = split1(v.z); h.z = s2.h; l.z = s2.l;
                hl s3 = split1(v.w); h.w = s3.h; l.w = s3.l;
                *(bf16x4*)&Ah[r * LDA + c] = h;
                *(bf16x4*)&Al[r * LDA + c] = l;
            }
        }
        // ---- stage B ----
        if constexpr (BMODE == 1) {
            glds16(bH0, &Bh[tid * 8]); glds16(bH1, &Bh[(256 + tid) * 8]);
            glds16(bL0, &Bl[tid * 8]); glds16(bL1, &Bl[(256 + tid) * 8]);
            bH0 += 32; bH1 += 32; bL0 += 32; bL1 += 32;
        } else {
#pragma unroll
            for (int j = 0; j < 4; ++j) {
                const int idx = j * 256 + tid;
                const int r = idx >> 3, c = (idx & 7) * 4;
                const float4 v = *(const float4*)bF[j]; bF[j] += 32;
                bf16x4 h, l;
                hl s0 = split1(v.x); h.x = s0.h; l.x = s0.l;
                hl s1 = split1(v.y); h.y = s1.h; l.y = s1.l;
                hl s2 = split1(v.z); h.z = s2.h; l.z = s2.l;
                hl s3 = split1(v.w); h.w = s3.h; l.w = s3.l;
                *(bf16x4*)&Bh[r * LDB + c] = h;
                *(bf16x4*)&Bl[r * LDB + c] = l;
            }
        }
        __syncthreads();

        // two K=16 halves; 8 frags live at a time (32 VGPR) + 64 acc
#pragma unroll
        for (int kk = 0; kk < 2; ++kk) {
            const int ca = (kk * 16 + kb8) ^ swA;
            const int cb = (kk * 16 + kb8) ^ swB;
            bf16x8 ah0 = *(const bf16x8*)&Ah[aRow0 + ca];
            bf16x8 ah1 = *(const bf16x8*)&Ah[aRow1 + ca];
            bf16x8 al0 = *(const bf16x8*)&Al[aRow0 + ca];
            bf16x8 al1 = *(const bf16x8*)&Al[aRow1 + ca];
            bf16x8 bh0 = *(const bf16x8*)&Bh[bRow0 + cb];
            bf16x8 bh1 = *(const bf16x8*)&Bh[bRow1 + cb];
            bf16x8 bl0 = *(const bf16x8*)&Bl[bRow0 + cb];
            bf16x8 bl1 = *(const bf16x8*)&Bl[bRow1 + cb];

            acc[0][0] = __builtin_amdgcn_mfma_f32_32x32x16_bf16(ah0, bh0, acc[0][0], 0, 0, 0);
            acc[0][1] = __builtin_amdgcn_mfma_f32_32x32x16_bf16(ah0, bh1, acc[0][1], 0, 0, 0);
            acc[1][0] = __builtin_amdgcn_mfma_f32_32x32x16_bf16(ah1, bh0, acc[1][0], 0, 0, 0);
            acc[1][1] = __builtin_amdgcn_mfma_f32_32x32x16_bf16(ah1, bh1, acc[1][1], 0, 0, 0);

            acc[0][0] = __builtin_amdgcn_mfma_f32_32x32x16_bf16(al0, bh0, acc[0][0], 0, 0, 0);
            acc[0][1] = __builtin_amdgcn_mfma_f32_32x32x16_bf16(al0, bh1, acc[0][1], 0, 0, 0);
            acc[1][0] = __builtin_amdgcn_mfma_f32_32x32x16_bf16(al1, bh0, acc[1][0], 0, 0, 0);
            acc[1][1] = __builtin_amdgcn_mfma_f32_32x32x16_bf16(al1, bh1, acc[1][1], 0, 0, 0);

            acc[0][0] = __builtin_amdgcn_mfma_f32_32x32x16_bf16(ah0, bl0, acc[0][0], 0, 0, 0);
            acc[0][1] = __builtin_amdgcn_mfma_f32_32x32x16_bf16(ah0, bl1, acc[0][1], 0, 0, 0);
            acc[1][0] = __builtin_amdgcn_mfma_f32_32x32x16_bf16(ah1, bl0, acc[1][0], 0, 0, 0);
            acc[1][1] = __builtin_amdgcn_mfma_f32_32x32x16_bf16(ah1, bl1, acc[1][1], 0, 0, 0);
        }
    }

    // ---- epilogue: 32x32 D mapping col=lane&31, row=(q&3)+8*(q>>2)+4*(lane>>5) ----
    const int drow = 4 * (lane >> 5);
#pragma unroll
    for (int i = 0; i < 2; ++i)
#pragma unroll
        for (int j = 0; j < 2; ++j) {
            f32x16 a = acc[i][j];
#pragma unroll
            for (int q = 0; q < 16; ++q) {
                const int row = m0 + wm * 64 + i * 32 + (q & 3) + 8 * (q >> 2) + drow;
                const int col = n0 + wn * 64 + j * 32 + lr32;
                const long off = (long)z * sCz + (long)row * N + col;
                if constexpr (OMODE == 0) {
                    Cf[off] = a[q];
                } else {
                    hl s = split1(a[q]);
                    Cgh[off] = s.h; Cgl[off] = s.l;
                }
            }
        }
}

// ---------------------------------------------------------------------------
// elementwise: f32 -> (hi, lo) bf16 planes
// ---------------------------------------------------------------------------
__global__ __launch_bounds__(256) void split_pair(
    const float* __restrict__ x, bf16* __restrict__ h, bf16* __restrict__ l, long n4)
{
    long i = (long)blockIdx.x * 256 + threadIdx.x;
    const long stride = (long)gridDim.x * 256;
    for (; i < n4; i += stride) {
        const float4 v = ((const float4*)x)[i];
        bf16x4 hh, ll;
        hl s0 = split1(v.x); hh.x = s0.h; ll.x = s0.l;
        hl s1 = split1(v.y); hh.y = s1.h; ll.y = s1.l;
        hl s2 = split1(v.z); hh.z = s2.h; ll.z = s2.l;
        hl s3 = split1(v.w); hh.w = s3.h; ll.w = s3.l;
        ((bf16x4*)h)[i] = hh;
        ((bf16x4*)l)[i] = ll;
    }
}

// ---------------------------------------------------------------------------
// masked softmax, one wave per 1024-elem row (no LDS, shuffle-only reduce)
// ---------------------------------------------------------------------------
__global__ __launch_bounds__(256) void softmax_wave(
    float* __restrict__ data, const int* __restrict__ lens)
{
    const int tid  = threadIdx.x;
    const int lane = tid & 63;
    const int row  = blockIdx.x * 4 + (tid >> 6);
    const int len  = lens[row >> 10];
    float* p = data + (long)row * 1024;

    float4 v[4];
#pragma unroll
    for (int q = 0; q < 4; ++q) v[q] = *(const float4*)(p + 4 * (lane + 64 * q));

    float m = -INFINITY;
#pragma unroll
    for (int q = 0; q < 4; ++q) {
        const int base = 4 * (lane + 64 * q);
        if (base + 0 < len) m = fmaxf(m, v[q].x);
        if (base + 1 < len) m = fmaxf(m, v[q].y);
        if (base + 2 < len) m = fmaxf(m, v[q].z);
        if (base + 3 < len) m = fmaxf(m, v[q].w);
    }
#pragma unroll
    for (int off = 32; off >= 1; off >>= 1) m = fmaxf(m, __shfl_xor(m, off));

    float s = 0.0f;
    float4 e[4];
#pragma unroll
    for (int q = 0; q < 4; ++q) {
        const int base = 4 * (lane + 64 * q);
        e[q].x = (base + 0 < len) ? __expf(v[q].x - m) : 0.0f;
        e[q].y = (base + 1 < len) ? __expf(v[q].y - m) : 0.0f;
        e[q].z = (base + 2 < len) ? __expf(v[q].z - m) : 0.0f;
        e[q].w = (base + 3 < len) ? __expf(v[q].w - m) : 0.0f;
        s += e[q].x + e[q].y + e[q].z + e[q].w;
    }
#pragma unroll
    for (int off = 32; off >= 1; off >>= 1) s += __shfl_xor(s, off);

    const float inv = 1.0f / s;
#pragma unroll
    for (int q = 0; q < 4; ++q) {
        float4 o; o.x = e[q].x * inv; o.y = e[q].y * inv; o.z = e[q].z * inv; o.w = e[q].w * inv;
        *(float4*)(p + 4 * (lane + 64 * q)) = o;
    }
}

// ---------------------------------------------------------------------------
// round-2 proven fallback GEMM (tier C, 16x16x32)
// ---------------------------------------------------------------------------
__global__ __launch_bounds__(256) void gemm_bt_split(
    const float* __restrict__ A, const float* __restrict__ Bmat,
    float* __restrict__ C, int M, int N, int K,
    long sAz, long sBz, long sCz)
{
    __shared__ __align__(16) bf16 Ah[128][40];
    __shared__ __align__(16) bf16 Al[128][40];
    __shared__ __align__(16) bf16 Bh[128][40];
    __shared__ __align__(16) bf16 Bl[128][40];

    const int tid  = threadIdx.x;
    const int lane = tid & 63;
    const int wid  = tid >> 6;
    const int wm   = wid >> 1;
    const int wn   = wid & 1;
    const int z    = blockIdx.z;
    const long aBase = (long)z * sAz;
    const long bBase = (long)z * sBz;
    const long cBase = (long)z * sCz;
    const int m0 = blockIdx.x * 128;
    const int n0 = blockIdx.y * 128;

    f32x4 acc[4][4];
#pragma unroll
    for (int i = 0; i < 4; ++i)
#pragma unroll
        for (int j = 0; j < 4; ++j) acc[i][j] = (f32x4)0.0f;

    const int lr = lane & 15;
    const int lk = (lane >> 4) * 8;

    for (int kt = 0; kt < K; kt += 32) {
        __syncthreads();
#pragma unroll
        for (int j = 0; j < 4; ++j) {
            const int idx = j * 256 + tid;
            const int r   = idx >> 3;
            const int c   = (idx & 7) * 4;
            const float4 va = *(const float4*)(A    + aBase + (long)(m0 + r) * K + kt + c);
            const float4 vb = *(const float4*)(Bmat + bBase + (long)(n0 + r) * K + kt + c);
            bf16x4 ah, al, bh, bl;
            hl a0 = split1(va.x); ah.x = a0.h; al.x = a0.l;
            hl a1 = split1(va.y); ah.y = a1.h; al.y = a1.l;
            hl a2 = split1(va.z); ah.z = a2.h; al.z = a2.l;
            hl a3 = split1(va.w); ah.w = a3.h; al.w = a3.l;
            hl b0 = split1(vb.x); bh.x = b0.h; bl.x = b0.l;
            hl b1 = split1(vb.y); bh.y = b1.h; bl.y = b1.l;
            hl b2 = split1(vb.z); bh.z = b2.h; bl.z = b2.l;
            hl b3 = split1(vb.w); bh.w = b3.h; bl.w = b3.l;
            *(bf16x4*)&Ah[r][c] = ah; *(bf16x4*)&Al[r][c] = al;
            *(bf16x4*)&Bh[r][c] = bh; *(bf16x4*)&Bl[r][c] = bl;
        }
        __syncthreads();

        bf16x8 afh[4], afl[4], bfh[4], bfl[4];
#pragma unroll
        for (int i = 0; i < 4; ++i) {
            afh[i] = *(const bf16x8*)&Ah[wm * 64 + i * 16 + lr][lk];
            afl[i] = *(const bf16x8*)&Al[wm * 64 + i * 16 + lr][lk];
            bfh[i] = *(const bf16x8*)&Bh[wn * 64 + i * 16 + lr][lk];
            bfl[i] = *(const bf16x8*)&Bl[wn * 64 + i * 16 + lr][lk];
        }
#pragma unroll
        for (int i = 0; i < 4; ++i)
#pragma unroll
            for (int j = 0; j < 4; ++j) {
                acc[i][j] = __builtin_amdgcn_mfma_f32_16x16x32_bf16(afh[i], bfh[j], acc[i][j], 0, 0, 0);
                acc[i][j] = __builtin_amdgcn_mfma_f32_16x16x32_bf16(afl[i], bfh[j], acc[i][j], 0, 0, 0);
                acc[i][j] = __builtin_amdgcn_mfma_f32_16x16x32_bf16(afh[i], bfl[j], acc[i][j], 0, 0, 0);
            }
    }

    const int rr = (lane >> 4) * 4;
#pragma unroll
    for (int i = 0; i < 4; ++i)
#pragma unroll
        for (int j = 0; j < 4; ++j)
#pragma unroll
            for (int q = 0; q < 4; ++q)
                C[cBase + (long)(m0 + wm * 64 + i * 16 + rr + q) * N
                        + (n0 + wn * 64 + j * 16 + (lane & 15))] = acc[i][j][q];
}

extern "C" void kernel_launch(void* const* d_in, const int* in_sizes, int n_in,
                              void* d_out, int out_size, void* d_ws, size_t ws_size,
                              hipStream_t stream)
{
    const float* source         = (const float*)d_in[0];  // [16,1024,1024]
    const float* memory_bank    = (const float*)d_in[1];  // [16,1024,1024]
    const int*   memory_lengths = (const int*)  d_in[2];  // [16]
    const float* W_in           = (const float*)d_in[3];  // [1024,1024]
    float* out = (float*)d_out;                           // [16,1024,1024]
    char*  ws  = (char*)d_ws;

    const size_t MB = 1ull << 20;
    const long Z = 1024 * 1024;   // per-batch plane stride (elements)

    if (ws_size >= 197 * MB) {
        // tier A+: everything pre-split, all GEMM staging via global_load_lds
        bf16* htH = (bf16*)(ws);            bf16* htL = (bf16*)(ws + 32 * MB);
        bf16* WH  = (bf16*)(ws + 64 * MB);  bf16* WL  = (bf16*)(ws + 66 * MB);
        bf16* mbH = (bf16*)(ws + 68 * MB);  bf16* mbL = (bf16*)(ws + 100 * MB);
        bf16* srH = (bf16*)(ws + 132 * MB); bf16* srL = (bf16*)(ws + 164 * MB);
        split_pair<<<512,  256, 0, stream>>>(W_in,        WH,  WL,  (1l  << 20) / 4);
        split_pair<<<2048, 256, 0, stream>>>(memory_bank, mbH, mbL, (16l << 20) / 4);
        split_pair<<<2048, 256, 0, stream>>>(source,      srH, srL, (16l << 20) / 4);
        gemm3<1,1,1><<<1024, 256, 0, stream>>>(nullptr, srH, srL, nullptr, WH, WL,
            nullptr, htH, htL, 16384, 1024, 1024, 0, 0, 0, 128, 8);
        gemm3<1,1,0><<<1024, 256, 0, stream>>>(nullptr, htH, htL, nullptr, mbH, mbL,
            out, nullptr, nullptr, 1024, 1024, 1024, Z, Z, Z, 8, 8);
    } else if (ws_size >= 133 * MB) {
        // tier A
        bf16* htH = (bf16*)(ws);            bf16* htL = (bf16*)(ws + 32 * MB);
        bf16* WH  = (bf16*)(ws + 64 * MB);  bf16* WL  = (bf16*)(ws + 66 * MB);
        bf16* mbH = (bf16*)(ws + 68 * MB);  bf16* mbL = (bf16*)(ws + 100 * MB);
        split_pair<<<512,  256, 0, stream>>>(W_in,        WH,  WL,  (1l  << 20) / 4);
        split_pair<<<2048, 256, 0, stream>>>(memory_bank, mbH, mbL, (16l << 20) / 4);
        gemm3<0,1,1><<<1024, 256, 0, stream>>>(source, nullptr, nullptr, nullptr, WH, WL,
            nullptr, htH, htL, 16384, 1024, 1024, 0, 0, 0, 128, 8);
        gemm3<1,1,0><<<1024, 256, 0, stream>>>(nullptr, htH, htL, nullptr, mbH, mbL,
            out, nullptr, nullptr, 1024, 1024, 1024, Z, Z, Z, 8, 8);
    } else if (ws_size >= 69 * MB) {
        // tier B
        bf16* htH = (bf16*)(ws);            bf16* htL = (bf16*)(ws + 32 * MB);
        bf16* WH  = (bf16*)(ws + 64 * MB);  bf16* WL  = (bf16*)(ws + 66 * MB);
        split_pair<<<512, 256, 0, stream>>>(W_in, WH, WL, (1l << 20) / 4);
        gemm3<0,1,1><<<1024, 256, 0, stream>>>(source, nullptr, nullptr, nullptr, WH, WL,
            nullptr, htH, htL, 16384, 1024, 1024, 0, 0, 0, 128, 8);
        gemm3<1,0,0><<<1024, 256, 0, stream>>>(nullptr, htH, htL, memory_bank, nullptr, nullptr,
            out, nullptr, nullptr, 1024, 1024, 1024, Z, Z, Z, 8, 8);
    } else {
        // tier C: proven fallback
        float* ht = (float*)ws;
        gemm_bt_split<<<dim3(128, 8, 1), 256, 0, stream>>>(
            source, W_in, ht, 16384, 1024, 1024, 0, 0, 0);
        gemm_bt_split<<<dim3(8, 8, 16), 256, 0, stream>>>(
            ht, memory_bank, out, 1024, 1024, 1024, Z, Z, Z);
    }

    softmax_wave<<<4096, 256, 0, stream>>>(out, memory_lengths);
}